// Round 1
// baseline (410.925 us; speedup 1.0000x reference)
//
#include <hip/hip_runtime.h>
#include <hip/hip_bf16.h>
#include <math.h>

#define Bb 64
#define Ss 512
#define Dd 768
#define Hh 512
#define PKk 2304
#define NEGF (-1e30f)

// ws float offsets
#define P_OFF   0u           // spanmax partials: 192*8*768 = 1179648
#define ENT_OFF 1179648u     // ent (B,3,D) = 147456
#define EA_OFF  1327104u     // e state A
#define EB_OFF  1474560u     // e state B
#define S_OFF   1622016u     // s (192*5), padded to 1024
#define VP_OFF  1623040u     // vr partials 4*192*512 = 393216
#define GP_OFF  2016256u     // gate partials 4*192*768 = 589824
#define PP_OFF  2606080u     // pred partials 8*64*512 = 262144
// total 2868224 floats = 11.5 MB

__device__ __forceinline__ float sigmoidf_(float x){ return 1.0f/(1.0f+expf(-x)); }

// ---- span max: partials over 64-row chunks ----
__global__ __launch_bounds__(192) void k_spanmax_partial(
    const float* __restrict__ enc, const int* __restrict__ ent_pos, float* __restrict__ ws)
{
    int bi = blockIdx.y; int c = blockIdx.x; int t = threadIdx.x;
    int b = bi/3;
    int st = ent_pos[bi*2+0], en = ent_pos[bi*2+1];
    int r0 = max(st, c*64), r1 = min(en, c*64+63);
    float4 m = make_float4(NEGF,NEGF,NEGF,NEGF);
    const float4* e4 = (const float4*)enc;
    for (int r=r0; r<=r1; ++r){
        float4 v = e4[(size_t)(b*Ss + r)*192 + t];
        m.x=fmaxf(m.x,v.x); m.y=fmaxf(m.y,v.y); m.z=fmaxf(m.z,v.z); m.w=fmaxf(m.w,v.w);
    }
    ((float4*)(ws+P_OFF))[(bi*8+c)*192 + t] = m;
}

// ---- reduce partials -> ent, init e-state, ent_score output ----
__global__ __launch_bounds__(256) void k_spanmax_reduce(
    const float* __restrict__ projW, const float* __restrict__ projb,
    float* __restrict__ ws, float* __restrict__ out)
{
    __shared__ float red[256];
    int bi = blockIdx.x; int t = threadIdx.x;
    float local = 0.f;
    if (t < 192){
        float4 m = make_float4(NEGF,NEGF,NEGF,NEGF);
        const float4* p4 = (const float4*)(ws+P_OFF);
        for (int c=0;c<8;++c){
            float4 v = p4[(bi*8+c)*192+t];
            m.x=fmaxf(m.x,v.x); m.y=fmaxf(m.y,v.y); m.z=fmaxf(m.z,v.z); m.w=fmaxf(m.w,v.w);
        }
        ((float4*)(ws+ENT_OFF))[bi*192+t] = m;
        ((float4*)(ws+EA_OFF))[bi*192+t] = m;
        float4 w = ((const float4*)projW)[t];
        local = m.x*w.x + m.y*w.y + m.z*w.z + m.w*w.w;
    }
    red[t]=local; __syncthreads();
    for (int off=128; off>0; off>>=1){ if (t<off) red[t]+=red[t+off]; __syncthreads(); }
    if (t==0) out[320 + bi] = sigmoidf_(red[0] + projb[0]);
}

// ---- pred head: split-K partials of relu-pre (64 x 512, K=2304 in 8 chunks) ----
__global__ __launch_bounds__(256) void k_pred_part(
    const float* __restrict__ predW1, float* __restrict__ ws)
{
    int ct = blockIdx.x, rb = blockIdx.y, ks = blockIdx.z;
    int tx = threadIdx.x & 31, ty = threadIdx.x >> 5;
    int row = rb*8+ty, col = ct*32+tx;
    const float* A = ws + ENT_OFF + (size_t)row*PKk + ks*288;
    const float* W = predW1 + (size_t)(ks*288)*Hh + col;
    float acc = 0.f;
    #pragma unroll 4
    for (int k=0;k<288;++k){ acc = fmaf(A[k], W[(size_t)k*Hh], acc); }
    ws[PP_OFF + ((size_t)(ks*64+row))*Hh + col] = acc;
}

// ---- pred finish: reduce + relu + (512->5) head -> rel ----
__global__ __launch_bounds__(256) void k_pred_fin(
    const float* __restrict__ pb1, const float* __restrict__ predW2,
    const float* __restrict__ pb2, float* __restrict__ ws, float* __restrict__ out)
{
    __shared__ float ph[512];
    __shared__ float red[256];
    int b = blockIdx.x, t = threadIdx.x;
    for (int c = t; c < 512; c += 256){
        float s = 0.f;
        for (int ks=0;ks<8;++ks) s += ws[PP_OFF + ((size_t)(ks*64+b))*Hh + c];
        ph[c] = fmaxf(s + pb1[c], 0.f);
    }
    __syncthreads();
    for (int c=0;c<5;++c){
        float local = ph[t]*predW2[t*5+c] + ph[t+256]*predW2[(t+256)*5+c];
        red[t]=local; __syncthreads();
        for (int off=128; off>0; off>>=1){ if (t<off) red[t]+=red[t+off]; __syncthreads(); }
        if (t==0) out[b*5+c] = red[0] + pb2[c];
        __syncthreads();
    }
}

// ---- vr GEMM partials: rows=(b,pair), A = concat(e_x,e_y), K=1536 split 4 ----
__global__ __launch_bounds__(256) void k_vr_part(
    const float* __restrict__ W1, const float* __restrict__ eSrc, float* __restrict__ ws)
{
    __shared__ float ldsA[16*128];
    int ct = blockIdx.x, rb = blockIdx.y, ks = blockIdx.z;
    int tx = threadIdx.x & 31, rg = threadIdx.x >> 5;
    int row0 = rb*16;
    int j = ct*64 + tx*2;
    float acc00=0,acc01=0,acc10=0,acc11=0;
    int rl = threadIdx.x >> 4;          // 0..15 staging row
    int kk0 = (threadIdx.x & 15) * 8;   // staging k offset
    int rowg = row0 + rl;
    int bb = rowg/3, p = rowg%3;
    int px = (p==0)?1:0;
    int py = (p==2)?1:2;
    for (int cc=0; cc<3; ++cc){
        int kbase = ks*384 + cc*128;
        int kglob = kbase + kk0;
        const float* src = (kglob < 768)
            ? (eSrc + (size_t)(bb*3+px)*Dd + kglob)
            : (eSrc + (size_t)(bb*3+py)*Dd + (kglob-768));
        float4 v0 = *(const float4*)(src);
        float4 v1 = *(const float4*)(src+4);
        float* dst = ldsA + rl*128 + kk0;
        *(float4*)dst = v0; *(float4*)(dst+4) = v1;
        __syncthreads();
        const float* Wp = W1 + (size_t)kbase*Hh + j;
        #pragma unroll 8
        for (int kk=0;kk<128;++kk){
            float a0 = ldsA[rg*128+kk];
            float a1 = ldsA[(rg+8)*128+kk];
            float2 w = *(const float2*)(Wp + (size_t)kk*Hh);
            acc00 = fmaf(a0,w.x,acc00); acc01 = fmaf(a0,w.y,acc01);
            acc10 = fmaf(a1,w.x,acc10); acc11 = fmaf(a1,w.y,acc11);
        }
        __syncthreads();
    }
    float* VP = ws + VP_OFF + ((size_t)(ks*192 + row0))*Hh;
    *(float2*)(VP + (size_t)rg*Hh + j)     = make_float2(acc00,acc01);
    *(float2*)(VP + (size_t)(rg+8)*Hh + j) = make_float2(acc10,acc11);
}

// ---- vr finish: reduce partials + relu -> hidden row; 512->5 head + sigmoid -> s ----
__global__ __launch_bounds__(256) void k_vr_sfin(
    const float* __restrict__ b1, const float* __restrict__ W2, const float* __restrict__ b2,
    float* __restrict__ ws)
{
    __shared__ float hrow[512];
    __shared__ float red[256];
    int row = blockIdx.x, t = threadIdx.x;
    for (int c=t;c<512;c+=256){
        float s = 0.f;
        for (int ks=0;ks<4;++ks) s += ws[VP_OFF + ((size_t)(ks*192+row))*Hh + c];
        hrow[c] = fmaxf(s + b1[c], 0.f);
    }
    __syncthreads();
    for (int c=0;c<5;++c){
        float local = hrow[t]*W2[t*5+c] + hrow[t+256]*W2[(t+256)*5+c];
        red[t]=local; __syncthreads();
        for (int off=128;off>0;off>>=1){ if (t<off) red[t]+=red[t+off]; __syncthreads(); }
        if (t==0) ws[S_OFF + row*5 + c] = sigmoidf_(red[0] + b2[c]);
        __syncthreads();
    }
}

// ---- gate GEMM partials: A = concat(u,e) with u = (s@Ar+Ar_b)*e built on the fly ----
__global__ __launch_bounds__(256) void k_gate_part(
    const float* __restrict__ gateW, const float* __restrict__ ArW, const float* __restrict__ Arb,
    const float* __restrict__ eSrc, float* __restrict__ ws)
{
    __shared__ float ldsA[16*128];
    int ct = blockIdx.x, rb = blockIdx.y, ks = blockIdx.z;
    int tx = threadIdx.x & 31, rg = threadIdx.x >> 5;
    int row0 = rb*16;
    int j = ct*64 + tx*2;
    float acc00=0,acc01=0,acc10=0,acc11=0;
    int rl = threadIdx.x >> 4, kk0 = (threadIdx.x & 15)*8;
    int rowg = row0 + rl;
    float s0=0,s1=0,s2=0,s3=0,s4=0;
    if (ks < 2){
        const float* sp = ws + S_OFF + rowg*5;
        s0=sp[0]; s1=sp[1]; s2=sp[2]; s3=sp[3]; s4=sp[4];
    }
    for (int cc=0; cc<3; ++cc){
        int kbase = ks*384 + cc*128;
        int kglob = kbase + kk0;
        float* dst = ldsA + rl*128 + kk0;
        if (kglob < 768){
            const float* ep = eSrc + (size_t)rowg*Dd + kglob;
            #pragma unroll
            for (int m=0;m<8;++m){
                int k = kglob+m;
                float a = Arb[k] + s0*ArW[k] + s1*ArW[768+k] + s2*ArW[1536+k]
                                 + s3*ArW[2304+k] + s4*ArW[3072+k];
                dst[m] = a * ep[m];
            }
        } else {
            const float* ep = eSrc + (size_t)rowg*Dd + (kglob-768);
            float4 v0 = *(const float4*)ep; float4 v1 = *(const float4*)(ep+4);
            *(float4*)dst = v0; *(float4*)(dst+4) = v1;
        }
        __syncthreads();
        const float* Wp = gateW + (size_t)kbase*Dd + j;
        #pragma unroll 8
        for (int kk=0;kk<128;++kk){
            float a0 = ldsA[rg*128+kk];
            float a1 = ldsA[(rg+8)*128+kk];
            float2 w = *(const float2*)(Wp + (size_t)kk*Dd);
            acc00 = fmaf(a0,w.x,acc00); acc01 = fmaf(a0,w.y,acc01);
            acc10 = fmaf(a1,w.x,acc10); acc11 = fmaf(a1,w.y,acc11);
        }
        __syncthreads();
    }
    float* GP = ws + GP_OFF + ((size_t)(ks*192 + row0))*Dd;
    *(float2*)(GP + (size_t)rg*Dd + j)     = make_float2(acc00,acc01);
    *(float2*)(GP + (size_t)(rg+8)*Dd + j) = make_float2(acc10,acc11);
}

// ---- gate finish: reduce + sigmoid + convex combine -> e_dst (and final output) ----
__global__ __launch_bounds__(256) void k_gate_fin(
    const float* __restrict__ gb, const float* __restrict__ ArW, const float* __restrict__ Arb,
    const float* __restrict__ eSrc, float* __restrict__ eDst,
    float* __restrict__ ws, float* __restrict__ finalOut)
{
    int idx = blockIdx.x*256 + threadIdx.x;   // 192*768
    int row = idx / Dd, jc = idx % Dd;
    float pre = gb[jc];
    for (int ks=0;ks<4;++ks) pre += ws[GP_OFF + ((size_t)(ks*192+row))*Dd + jc];
    float g = sigmoidf_(pre);
    const float* sp = ws + S_OFF + row*5;
    float a = Arb[jc] + sp[0]*ArW[jc] + sp[1]*ArW[768+jc] + sp[2]*ArW[1536+jc]
                      + sp[3]*ArW[2304+jc] + sp[4]*ArW[3072+jc];
    float e = eSrc[(size_t)row*Dd + jc];
    float u = a*e;
    float val = g*e + (1.f-g)*u;
    eDst[(size_t)row*Dd + jc] = val;
    if (finalOut) finalOut[idx] = val;
}

extern "C" void kernel_launch(void* const* d_in, const int* in_sizes, int n_in,
                              void* d_out, int out_size, void* d_ws, size_t ws_size,
                              hipStream_t stream)
{
    const float* enc     = (const float*)d_in[0];
    const int*   ent_pos = (const int*)d_in[1];
    const float* ArW     = (const float*)d_in[2];
    const float* Arb     = (const float*)d_in[3];
    const float* VrW1    = (const float*)d_in[4];
    const float* Vrb1    = (const float*)d_in[5];
    const float* VrW2    = (const float*)d_in[6];
    const float* Vrb2    = (const float*)d_in[7];
    const float* gateW   = (const float*)d_in[8];
    const float* gateb   = (const float*)d_in[9];
    const float* predW1  = (const float*)d_in[10];
    const float* predb1  = (const float*)d_in[11];
    const float* predW2  = (const float*)d_in[12];
    const float* predb2  = (const float*)d_in[13];
    const float* projW   = (const float*)d_in[14];
    const float* projb   = (const float*)d_in[15];
    float* out = (float*)d_out;
    float* ws  = (float*)d_ws;

    hipLaunchKernelGGL(k_spanmax_partial, dim3(8,192), dim3(192), 0, stream, enc, ent_pos, ws);
    hipLaunchKernelGGL(k_spanmax_reduce, dim3(192), dim3(256), 0, stream, projW, projb, ws, out);
    hipLaunchKernelGGL(k_pred_part, dim3(16,8,8), dim3(256), 0, stream, predW1, ws);
    hipLaunchKernelGGL(k_pred_fin, dim3(64), dim3(256), 0, stream, predb1, predW2, predb2, ws, out);
    for (int it=0; it<5; ++it){
        float* eS = ws + ((it&1)==0 ? EA_OFF : EB_OFF);
        float* eD = ws + ((it&1)==0 ? EB_OFF : EA_OFF);
        hipLaunchKernelGGL(k_vr_part,  dim3(8,12,4),  dim3(256), 0, stream, VrW1, eS, ws);
        hipLaunchKernelGGL(k_vr_sfin,  dim3(192),     dim3(256), 0, stream, Vrb1, VrW2, Vrb2, ws);
        hipLaunchKernelGGL(k_gate_part,dim3(12,12,4), dim3(256), 0, stream, gateW, ArW, Arb, eS, ws);
        hipLaunchKernelGGL(k_gate_fin, dim3(576),     dim3(256), 0, stream, gateb, ArW, Arb, eS, eD, ws,
                           (it==4) ? (out+512) : (float*)nullptr);
    }
}

// Round 3
// 181.315 us; speedup vs baseline: 2.2664x; 2.2664x over previous
//
#include <hip/hip_runtime.h>
#include <hip/hip_bf16.h>
#include <math.h>

#define NEGF (-1e30f)

// ws float offsets
#define P_OFF   0u           // spanmax partials: 192*8*768 = 1179648
#define ENT_OFF 1179648u     // ent (B,3,D) = 147456
#define EA_OFF  1327104u     // e state A
#define EB_OFF  1474560u     // e state B
#define SP_OFF  1622016u     // s-partials [16][192][5] = 15360
#define PP_OFF  1637376u     // pred partials 8*64*512 = 262144
// total 1899520 floats = 7.6 MB

__device__ __forceinline__ float sigmoidf_(float x){ return 1.0f/(1.0f+expf(-x)); }

// ---- span max: partials over 64-row chunks ----
__global__ __launch_bounds__(192) void k_spanmax_partial(
    const float* __restrict__ enc, const int* __restrict__ ent_pos, float* __restrict__ ws)
{
    int bi = blockIdx.y; int c = blockIdx.x; int t = threadIdx.x;
    int b = bi/3;
    int st = ent_pos[bi*2+0], en = ent_pos[bi*2+1];
    int r0 = max(st, c*64), r1 = min(en, c*64+63);
    float4 m = make_float4(NEGF,NEGF,NEGF,NEGF);
    const float4* e4 = (const float4*)enc;
    for (int r=r0; r<=r1; ++r){
        float4 v = e4[(size_t)(b*512 + r)*192 + t];
        m.x=fmaxf(m.x,v.x); m.y=fmaxf(m.y,v.y); m.z=fmaxf(m.z,v.z); m.w=fmaxf(m.w,v.w);
    }
    ((float4*)(ws+P_OFF))[(bi*8+c)*192 + t] = m;
}

// ---- reduce partials -> ent, init e-state, ent_score output ----
__global__ __launch_bounds__(256) void k_spanmax_reduce(
    const float* __restrict__ projW, const float* __restrict__ projb,
    float* __restrict__ ws, float* __restrict__ out)
{
    __shared__ float red[256];
    int bi = blockIdx.x; int t = threadIdx.x;
    float local = 0.f;
    if (t < 192){
        float4 m = make_float4(NEGF,NEGF,NEGF,NEGF);
        const float4* p4 = (const float4*)(ws+P_OFF);
        for (int c=0;c<8;++c){
            float4 v = p4[(bi*8+c)*192+t];
            m.x=fmaxf(m.x,v.x); m.y=fmaxf(m.y,v.y); m.z=fmaxf(m.z,v.z); m.w=fmaxf(m.w,v.w);
        }
        ((float4*)(ws+ENT_OFF))[bi*192+t] = m;
        ((float4*)(ws+EA_OFF))[bi*192+t] = m;
        float4 w = ((const float4*)projW)[t];
        local = m.x*w.x + m.y*w.y + m.z*w.z + m.w*w.w;
    }
    red[t]=local; __syncthreads();
    for (int off=128; off>0; off>>=1){ if (t<off) red[t]+=red[t+off]; __syncthreads(); }
    if (t==0) out[320 + bi] = sigmoidf_(red[0] + projb[0]);
}

// ---- pred head: split-K partials (64 x 512, K=2304 in 8 chunks) ----
__global__ __launch_bounds__(256) void k_pred_part(
    const float* __restrict__ predW1, float* __restrict__ ws)
{
    int ct = blockIdx.x, rb = blockIdx.y, ks = blockIdx.z;
    int tx = threadIdx.x & 31, ty = threadIdx.x >> 5;
    int row = rb*8+ty, col = ct*32+tx;
    const float* A = ws + ENT_OFF + (size_t)row*2304 + ks*288;
    const float* W = predW1 + (size_t)(ks*288)*512 + col;
    float acc = 0.f;
    #pragma unroll 4
    for (int k=0;k<288;++k){ acc = fmaf(A[k], W[(size_t)k*512], acc); }
    ws[PP_OFF + ((size_t)(ks*64+row))*512 + col] = acc;
}

// ---- pred finish: reduce + relu + (512->5) head -> rel ----
__global__ __launch_bounds__(256) void k_pred_fin(
    const float* __restrict__ pb1, const float* __restrict__ predW2,
    const float* __restrict__ pb2, float* __restrict__ ws, float* __restrict__ out)
{
    __shared__ float ph[512];
    __shared__ float red[256];
    int b = blockIdx.x, t = threadIdx.x;
    for (int c = t; c < 512; c += 256){
        float s = 0.f;
        for (int ks=0;ks<8;++ks) s += ws[PP_OFF + ((size_t)(ks*64+b))*512 + c];
        ph[c] = fmaxf(s + pb1[c], 0.f);
    }
    __syncthreads();
    for (int c=0;c<5;++c){
        float local = ph[t]*predW2[t*5+c] + ph[t+256]*predW2[(t+256)*5+c];
        red[t]=local; __syncthreads();
        for (int off=128; off>0; off>>=1){ if (t<off) red[t]+=red[t+off]; __syncthreads(); }
        if (t==0) out[b*5+c] = red[0] + pb2[c];
        __syncthreads();
    }
}

// ---- vr fused: full-K GEMM (shared-product trick) + relu + 512->5 head partials ----
// grid (16 ct, 32 bg), 256 thr. Block: 2 b's (6 rows), 32 hidden cols, K=1536.
__global__ __launch_bounds__(256) void k_vr_fused(
    const float* __restrict__ W1, const float* __restrict__ b1,
    const float* __restrict__ W2, const float* __restrict__ eSrc,
    float* __restrict__ ws)
{
    __shared__ float eL[4608];    // [2 b][3 p][768]
    __shared__ float red[2048];   // [kq16][tp16][8]
    int ct = blockIdx.x, bg = blockIdx.y;
    int t = threadIdx.x;
    int b0 = bg*2;
    const float* eBase = eSrc + (size_t)b0*2304;
    for (int idx=t; idx<4608; idx+=256) eL[idx] = eBase[idx];
    __syncthreads();

    int tp = t & 15;
    int kq = t >> 4;             // 0..15, K-chunk of 96
    int c0 = ct*32;
    int col = c0 + 2*tp;
    const float* Wp = W1 + (size_t)(kq*96)*512 + col;
    // half1 (k<768): P=e2 (row0), Q=e1 (rows1,2); half2: P=e3 (rows0,1), Q=e2 (row2)
    int off1 = (kq<8) ? (768 + kq*96) : (1536 + (kq-8)*96);
    int off2 = (kq<8) ? (      kq*96) : (768  + (kq-8)*96);
    const float* pP0 = eL + off1;
    const float* pQ0 = eL + off2;
    const float* pP1 = eL + 2304 + off1;
    const float* pQ1 = eL + 2304 + off2;
    float aP0x=0,aP0y=0,aQ0x=0,aQ0y=0,aP1x=0,aP1y=0,aQ1x=0,aQ1y=0;
    #pragma unroll 8
    for (int i=0;i<96;++i){
        float2 w = *(const float2*)(Wp + (size_t)i*512);
        float p0 = pP0[i], q0 = pQ0[i], p1 = pP1[i], q1 = pQ1[i];
        aP0x = fmaf(p0,w.x,aP0x); aP0y = fmaf(p0,w.y,aP0y);
        aQ0x = fmaf(q0,w.x,aQ0x); aQ0y = fmaf(q0,w.y,aQ0y);
        aP1x = fmaf(p1,w.x,aP1x); aP1y = fmaf(p1,w.y,aP1y);
        aQ1x = fmaf(q1,w.x,aQ1x); aQ1y = fmaf(q1,w.y,aQ1y);
    }
    float* rp = red + (kq*16 + tp)*8;
    rp[0]=aP0x; rp[1]=aP0y; rp[2]=aQ0x; rp[3]=aQ0y;
    rp[4]=aP1x; rp[5]=aP1y; rp[6]=aQ1x; rp[7]=aQ1y;
    __syncthreads();

    if (t < 64){
        int tc = t & 31, bb = t >> 5;
        int jb = bb*4 + (tc & 1);
        int rtp = tc >> 1;
        float SP1=0,SP2=0,SQ1=0,SQ2=0;
        #pragma unroll
        for (int k=0;k<8;++k){
            SP1 += red[(k*16+rtp)*8 + jb];
            SQ1 += red[(k*16+rtp)*8 + jb + 2];
            SP2 += red[((k+8)*16+rtp)*8 + jb];
            SQ2 += red[((k+8)*16+rtp)*8 + jb + 2];
        }
        int c = c0 + tc;
        float bv = b1[c];
        float h0 = fmaxf(SP1+SP2+bv, 0.f);
        float h1 = fmaxf(SQ1+SP2+bv, 0.f);
        float h2 = fmaxf(SQ1+SQ2+bv, 0.f);
        float w20 = W2[c*5+0], w21 = W2[c*5+1], w22 = W2[c*5+2], w23 = W2[c*5+3], w24 = W2[c*5+4];
        float pr[15] = { h0*w20,h0*w21,h0*w22,h0*w23,h0*w24,
                         h1*w20,h1*w21,h1*w22,h1*w23,h1*w24,
                         h2*w20,h2*w21,h2*w22,h2*w23,h2*w24 };
        #pragma unroll
        for (int j=0;j<15;++j){
            float v = pr[j];
            v += __shfl_down(v, 16, 32);
            v += __shfl_down(v, 8, 32);
            v += __shfl_down(v, 4, 32);
            v += __shfl_down(v, 2, 32);
            v += __shfl_down(v, 1, 32);
            pr[j] = v;
        }
        if (tc == 0){
            float* sp = ws + SP_OFF + ((size_t)ct*192 + (size_t)(b0+bb)*3)*5;
            #pragma unroll
            for (int j=0;j<15;++j) sp[j] = pr[j];
        }
    }
}

// ---- gate fused: finish s, build u, full-K gate GEMM, sigmoid + combine -> e' ----
// grid (24 ct, 32 bg), 256 thr. Block: 2 b's (6 rows), 32 out cols, K=1536.
__global__ __launch_bounds__(256) void k_gate_fused(
    const float* __restrict__ gW, const float* __restrict__ gb,
    const float* __restrict__ ArW, const float* __restrict__ Arb,
    const float* __restrict__ Vb2,
    const float* __restrict__ eSrc, float* __restrict__ eDst,
    float* __restrict__ ws, float* __restrict__ finalOut)
{
    __shared__ float eL[4608];
    __shared__ float uL[4608];
    __shared__ float red[3072];   // [16][16][12]
    __shared__ float sL[32];      // [bb][p][cc]
    int ct = blockIdx.x, bg = blockIdx.y;
    int t = threadIdx.x;
    int b0 = bg*2;
    const float* eBase = eSrc + (size_t)b0*2304;
    for (int idx=t; idx<4608; idx+=256) eL[idx] = eBase[idx];
    if (t < 30){
        int bb = t/15, pc = t%15, cc = pc%5;
        int row = (b0+bb)*3 + pc/5;
        float pre = Vb2[cc];
        #pragma unroll
        for (int q=0;q<16;++q) pre += ws[SP_OFF + ((size_t)q*192 + row)*5 + cc];
        sL[t] = sigmoidf_(pre);
    }
    __syncthreads();
    // build u = (s@Ar + Arb) * e
    for (int idx=t; idx<4608; idx+=256){
        int r = idx / 768;
        int k = idx - r*768;
        int bb = r / 3;  int p = r - bb*3;
        const float* s = sL + bb*15 + p*5;
        float a = Arb[k] + s[0]*ArW[k] + s[1]*ArW[768+k] + s[2]*ArW[1536+k]
                         + s[3]*ArW[2304+k] + s[4]*ArW[3072+k];
        uL[idx] = a * eL[idx];
    }
    __syncthreads();

    int tp = t & 15, kq = t >> 4;
    int c0 = ct*32;
    int col = c0 + 2*tp;
    const float* Wp = gW + (size_t)(kq*96)*768 + col;
    const float* A = (kq<8) ? uL : eL;
    int kb = (kq & 7)*96;
    float acc[6][2];
    #pragma unroll
    for (int r=0;r<6;++r){ acc[r][0]=0.f; acc[r][1]=0.f; }
    #pragma unroll 4
    for (int i=0;i<96;++i){
        float2 w = *(const float2*)(Wp + (size_t)i*768);
        #pragma unroll
        for (int r=0;r<6;++r){
            float a = A[r*768 + kb + i];
            acc[r][0] = fmaf(a, w.x, acc[r][0]);
            acc[r][1] = fmaf(a, w.y, acc[r][1]);
        }
    }
    float* rp = red + (kq*16+tp)*12;
    #pragma unroll
    for (int r=0;r<6;++r){ rp[r*2]=acc[r][0]; rp[r*2+1]=acc[r][1]; }
    __syncthreads();

    for (int o=t; o<192; o+=256){
        int tc = o & 31, rr = o >> 5;
        int bb = rr/3, p = rr - bb*3;
        int j = rr*2 + (tc&1);
        int rtp = tc >> 1;
        float gp = 0.f;
        #pragma unroll
        for (int k=0;k<16;++k) gp += red[(k*16+rtp)*12 + j];
        int jc = c0 + tc;
        float g = sigmoidf_(gp + gb[jc]);
        float e = eL[bb*2304 + p*768 + jc];
        float u = uL[bb*2304 + p*768 + jc];
        float val = g*e + (1.f-g)*u;
        size_t oi = ((size_t)(b0+bb)*3 + p)*768 + jc;
        eDst[oi] = val;
        if (finalOut) finalOut[oi] = val;
    }
}

extern "C" void kernel_launch(void* const* d_in, const int* in_sizes, int n_in,
                              void* d_out, int out_size, void* d_ws, size_t ws_size,
                              hipStream_t stream)
{
    const float* enc     = (const float*)d_in[0];
    const int*   ent_pos = (const int*)d_in[1];
    const float* ArW     = (const float*)d_in[2];
    const float* Arb     = (const float*)d_in[3];
    const float* VrW1    = (const float*)d_in[4];
    const float* Vrb1    = (const float*)d_in[5];
    const float* VrW2    = (const float*)d_in[6];
    const float* Vrb2    = (const float*)d_in[7];
    const float* gateW   = (const float*)d_in[8];
    const float* gateb   = (const float*)d_in[9];
    const float* predW1  = (const float*)d_in[10];
    const float* predb1  = (const float*)d_in[11];
    const float* predW2  = (const float*)d_in[12];
    const float* predb2  = (const float*)d_in[13];
    const float* projW   = (const float*)d_in[14];
    const float* projb   = (const float*)d_in[15];
    float* out = (float*)d_out;
    float* ws  = (float*)d_ws;

    hipLaunchKernelGGL(k_spanmax_partial, dim3(8,192), dim3(192), 0, stream, enc, ent_pos, ws);
    hipLaunchKernelGGL(k_spanmax_reduce, dim3(192), dim3(256), 0, stream, projW, projb, ws, out);
    hipLaunchKernelGGL(k_pred_part, dim3(16,8,8), dim3(256), 0, stream, predW1, ws);
    hipLaunchKernelGGL(k_pred_fin, dim3(64), dim3(256), 0, stream, predb1, predW2, predb2, ws, out);
    for (int it=0; it<5; ++it){
        float* eS = ws + ((it&1)==0 ? EA_OFF : EB_OFF);
        float* eD = ws + ((it&1)==0 ? EB_OFF : EA_OFF);
        hipLaunchKernelGGL(k_vr_fused,   dim3(16,32), dim3(256), 0, stream, VrW1, Vrb1, VrW2, eS, ws);
        hipLaunchKernelGGL(k_gate_fused, dim3(24,32), dim3(256), 0, stream, gateW, gateb, ArW, Arb, Vrb2,
                           eS, eD, ws, (it==4) ? (out+512) : (float*)nullptr);
    }
}